// Round 1
// baseline (350.202 us; speedup 1.0000x reference)
//
#include <hip/hip_runtime.h>
#include <math.h>

#define NB 24
#define DM 128
#define NH 8
#define DK 16
#define LL 512

// ---------------------------------------------------------------------------
// Kernel A: one block per (h,b). Fused QKV projection + query-axis-softmax
// attention. Writes head[b, h*16+v, m] to workspace.
//
// LDS: QV[l][0..15] = Q[k][l], QV[l][16..31] = V[v][l]   (exactly 64 KB)
// K columns never touch LDS: thread t computes K columns l=t,t+256 in phase 1
// and consumes them as output columns m=t,t+256 in phase 2 (register-resident).
// ---------------------------------------------------------------------------
__global__ __launch_bounds__(256, 1)
void attn_fused(const float* __restrict__ x,
                const float* __restrict__ Wq,
                const float* __restrict__ Wk,
                const float* __restrict__ Wv,
                float* __restrict__ head)
{
    __shared__ __align__(16) float QV[LL][32];

    const int hb  = blockIdx.x;
    const int h   = hb / NB;
    const int b   = hb % NB;
    const int tid = threadIdx.x;

    const float* __restrict__ xb = x + (size_t)b * DM * LL;
    const size_t woff = (size_t)(h * NB + b) * DK * DM;
    const float* __restrict__ wq = Wq + woff;
    const float* __restrict__ wk = Wk + woff;
    const float* __restrict__ wv = Wv + woff;

    float kv[2][DK];  // K columns for m = tid, tid+256

    // ---- Phase 1: project QKV for columns l = tid, tid+256 ----
    #pragma unroll
    for (int pass = 0; pass < 2; ++pass) {
        const int l = tid + pass * 256;
        float aq[DK], ak[DK], av[DK];
        #pragma unroll
        for (int k = 0; k < DK; ++k) { aq[k] = 0.f; ak[k] = 0.f; av[k] = 0.f; }
        const float* __restrict__ xcol = xb + l;
        for (int d = 0; d < DM; ++d) {
            const float xv = xcol[d * LL];        // coalesced across lanes
            #pragma unroll
            for (int k = 0; k < DK; ++k) {        // W reads wave-uniform -> s_load
                aq[k] = fmaf(wq[k * DM + d], xv, aq[k]);
                ak[k] = fmaf(wk[k * DM + d], xv, ak[k]);
                av[k] = fmaf(wv[k * DM + d], xv, av[k]);
            }
        }
        #pragma unroll
        for (int k = 0; k < DK; ++k) kv[pass][k] = ak[k];
        #pragma unroll
        for (int c = 0; c < 4; ++c) {
            float4 q4 = make_float4(aq[4*c], aq[4*c+1], aq[4*c+2], aq[4*c+3]);
            float4 v4 = make_float4(av[4*c], av[4*c+1], av[4*c+2], av[4*c+3]);
            *reinterpret_cast<float4*>(&QV[l][4 * c])      = q4;
            *reinterpret_cast<float4*>(&QV[l][16 + 4 * c]) = v4;
        }
    }
    __syncthreads();

    // ---- Phase 2: per output column m, online softmax over l (query axis) ----
    const int m0 = tid;
    const int m1 = tid + 256;
    float mx0 = -1e30f, mx1 = -1e30f, sm0 = 0.f, sm1 = 0.f;
    float acc0[DK], acc1[DK];
    #pragma unroll
    for (int v = 0; v < DK; ++v) { acc0[v] = 0.f; acc1[v] = 0.f; }

    for (int l = 0; l < LL; ++l) {
        float qv[16], vv[16];
        #pragma unroll
        for (int c = 0; c < 4; ++c) {             // broadcast ds_read_b128 x8
            float4 t = *reinterpret_cast<const float4*>(&QV[l][4 * c]);
            qv[4*c] = t.x; qv[4*c+1] = t.y; qv[4*c+2] = t.z; qv[4*c+3] = t.w;
            float4 u = *reinterpret_cast<const float4*>(&QV[l][16 + 4 * c]);
            vv[4*c] = u.x; vv[4*c+1] = u.y; vv[4*c+2] = u.z; vv[4*c+3] = u.w;
        }
        float s0 = 0.f, s1 = 0.f;
        #pragma unroll
        for (int k = 0; k < DK; ++k) {
            s0 = fmaf(qv[k], kv[0][k], s0);
            s1 = fmaf(qv[k], kv[1][k], s1);
        }
        s0 *= 0.25f; s1 *= 0.25f;
        if (s0 > mx0) {                            // rare (~7 of 512 iters)
            const float sc = __expf(mx0 - s0);
            sm0 *= sc;
            #pragma unroll
            for (int v = 0; v < DK; ++v) acc0[v] *= sc;
            mx0 = s0;
        }
        if (s1 > mx1) {
            const float sc = __expf(mx1 - s1);
            sm1 *= sc;
            #pragma unroll
            for (int v = 0; v < DK; ++v) acc1[v] *= sc;
            mx1 = s1;
        }
        const float p0 = __expf(s0 - mx0);
        const float p1 = __expf(s1 - mx1);
        sm0 += p0; sm1 += p1;
        #pragma unroll
        for (int v = 0; v < DK; ++v) {
            acc0[v] = fmaf(vv[v], p0, acc0[v]);
            acc1[v] = fmaf(vv[v], p1, acc1[v]);
        }
    }

    float* __restrict__ hout = head + ((size_t)b * (NH * DK) + h * DK) * LL;
    const float inv0 = 1.f / sm0;
    const float inv1 = 1.f / sm1;
    #pragma unroll
    for (int v = 0; v < DK; ++v) {
        hout[v * LL + m0] = acc0[v] * inv0;        // coalesced over m
        hout[v * LL + m1] = acc1[v] * inv1;
    }
}

// ---------------------------------------------------------------------------
// Kernel B: out[b] = Wo[b] (128x128) @ head[b] (128x512)
// grid: NB*8 blocks; each block does 64 columns. Thread: 32 output rows.
// ---------------------------------------------------------------------------
__global__ __launch_bounds__(256, 1)
void out_proj(const float* __restrict__ Wo,
              const float* __restrict__ head,
              float* __restrict__ out)
{
    const int bb    = blockIdx.x;
    const int b     = bb / 8;
    const int chunk = bb % 8;
    const int tid   = threadIdx.x;
    const int l     = chunk * 64 + (tid & 63);
    const int og    = (tid >> 6) * 32;  // wave-uniform o-range

    const float* __restrict__ wo = Wo + (size_t)b * DM * DM;
    const float* __restrict__ hd = head + (size_t)b * DM * LL + l;

    float acc[32];
    #pragma unroll
    for (int i = 0; i < 32; ++i) acc[i] = 0.f;

    for (int d = 0; d < DM; ++d) {
        const float hv = hd[d * LL];               // coalesced across lanes
        #pragma unroll
        for (int i = 0; i < 32; ++i)               // Wo wave-uniform -> s_load
            acc[i] = fmaf(wo[(og + i) * DM + d], hv, acc[i]);
    }

    float* __restrict__ ob = out + (size_t)b * DM * LL + l;
    #pragma unroll
    for (int i = 0; i < 32; ++i)
        ob[(og + i) * LL] = acc[i];
}

extern "C" void kernel_launch(void* const* d_in, const int* in_sizes, int n_in,
                              void* d_out, int out_size, void* d_ws, size_t ws_size,
                              hipStream_t stream) {
    const float* x  = (const float*)d_in[0];
    const float* Wq = (const float*)d_in[1];
    const float* Wk = (const float*)d_in[2];
    const float* Wv = (const float*)d_in[3];
    const float* Wo = (const float*)d_in[4];
    float* out  = (float*)d_out;
    float* head = (float*)d_ws;   // NB*DM*LL floats = 6.29 MB scratch

    attn_fused<<<NH * NB, 256, 0, stream>>>(x, Wq, Wk, Wv, head);
    out_proj<<<NB * 8, 256, 0, stream>>>(Wo, head, out);
}

// Round 3
// 241.118 us; speedup vs baseline: 1.4524x; 1.4524x over previous
//
#include <hip/hip_runtime.h>
#include <math.h>

#define NB 24
#define DM 128
#define NH 8
#define DK 16
#define LL 512
#define HB (NH * NB)   // 192

// ---------------------------------------------------------------------------
// Workspace layout (floats):
//   QV   [HB][LL][32]      q = [0:16], v = [16:32]     3,145,728 floats
//   K    [HB][DK][LL]                                  1,572,864
//   part [HB][4][18][LL]   fields: 0=mx 1=sm 2+v=acc   7,077,888
//   head [NB][DM][LL]                                  1,572,864
// total 13,369,344 floats = 53.5 MB
// ---------------------------------------------------------------------------
#define QV_OFF   0
#define K_OFF    3145728
#define PART_OFF 4718592
#define HEAD_OFF 11796480

// ---------------------------------------------------------------------------
// Kernel 1: QKV projection. 768 blocks = (hb, l-chunk of 128). 256 threads:
// thread = (l = chunk*128 + tid&127, k-group g = tid>>7 covering 8 k's).
// x loads coalesced; W loads wave-uniform (s_load).
// ---------------------------------------------------------------------------
__global__ __launch_bounds__(256)
void qkv_proj(const float* __restrict__ x,
              const float* __restrict__ Wq,
              const float* __restrict__ Wk,
              const float* __restrict__ Wv,
              float* __restrict__ qvbuf,
              float* __restrict__ kbuf)
{
    const int hb = blockIdx.x >> 2;
    const int lc = blockIdx.x & 3;
    const int tid = threadIdx.x;
    const int l = lc * 128 + (tid & 127);
    const int g = tid >> 7;                       // wave-uniform

    const int b = hb % NB;
    const float* __restrict__ xb = x + (size_t)b * DM * LL + l;
    const size_t woff = (size_t)hb * DK * DM + (size_t)(g * 8) * DM;
    const float* __restrict__ wq = Wq + woff;
    const float* __restrict__ wk = Wk + woff;
    const float* __restrict__ wv = Wv + woff;

    float aq[8], ak[8], av[8];
    #pragma unroll
    for (int j = 0; j < 8; ++j) { aq[j] = 0.f; ak[j] = 0.f; av[j] = 0.f; }

    #pragma unroll 4
    for (int d = 0; d < DM; ++d) {
        const float xv = xb[(size_t)d * LL];      // coalesced
        #pragma unroll
        for (int j = 0; j < 8; ++j) {             // W uniform -> s_load
            aq[j] = fmaf(wq[j * DM + d], xv, aq[j]);
            ak[j] = fmaf(wk[j * DM + d], xv, ak[j]);
            av[j] = fmaf(wv[j * DM + d], xv, av[j]);
        }
    }

    // Q,V -> interleaved row layout [hb][l][32]
    float* __restrict__ qvrow = qvbuf + ((size_t)hb * LL + l) * 32 + g * 8;
    *reinterpret_cast<float4*>(qvrow)      = make_float4(aq[0], aq[1], aq[2], aq[3]);
    *reinterpret_cast<float4*>(qvrow + 4)  = make_float4(aq[4], aq[5], aq[6], aq[7]);
    *reinterpret_cast<float4*>(qvrow + 16) = make_float4(av[0], av[1], av[2], av[3]);
    *reinterpret_cast<float4*>(qvrow + 20) = make_float4(av[4], av[5], av[6], av[7]);

    // K -> [hb][k][l] (coalesced along l)
    float* __restrict__ kout = kbuf + ((size_t)hb * DK + g * 8) * LL + l;
    #pragma unroll
    for (int j = 0; j < 8; ++j)
        kout[(size_t)j * LL] = ak[j];
}

// ---------------------------------------------------------------------------
// Kernel 2: partial attention. 768 blocks = (hb, l-chunk of 128 rows).
// LDS holds the chunk's 128 QV rows (16 KB). Each thread owns output
// columns m = tid, tid+256 (K columns register-resident, 0.25 prefolded),
// runs online softmax over the 128 rows, writes partial (mx, sm, acc[16]).
// ---------------------------------------------------------------------------
__global__ __launch_bounds__(256)
void attn_part(const float* __restrict__ qvbuf,
               const float* __restrict__ kbuf,
               float* __restrict__ part)
{
    __shared__ __align__(16) float4 QVs[128][8];   // 16 KB

    const int hb = blockIdx.x >> 2;
    const int lc = blockIdx.x & 3;
    const int tid = threadIdx.x;

    // stage 128 rows x 32 floats (1024 float4s), fully coalesced
    const float4* __restrict__ src =
        reinterpret_cast<const float4*>(qvbuf + ((size_t)hb * LL + lc * 128) * 32);
    #pragma unroll
    for (int i = tid; i < 1024; i += 256)
        QVs[i >> 3][i & 7] = src[i];

    // K columns for m0 = tid, m1 = tid + 256 (scale 0.25 folded in)
    const int m0 = tid, m1 = tid + 256;
    float kv0[DK], kv1[DK];
    const float* __restrict__ kb = kbuf + (size_t)hb * DK * LL;
    #pragma unroll
    for (int k = 0; k < DK; ++k) {
        kv0[k] = 0.25f * kb[(size_t)k * LL + m0];
        kv1[k] = 0.25f * kb[(size_t)k * LL + m1];
    }
    __syncthreads();

    float mx0 = -1e30f, mx1 = -1e30f, sm0 = 0.f, sm1 = 0.f;
    float acc0[DK], acc1[DK];
    #pragma unroll
    for (int v = 0; v < DK; ++v) { acc0[v] = 0.f; acc1[v] = 0.f; }

    for (int l = 0; l < 128; ++l) {
        float qr[16], vr[16];
        #pragma unroll
        for (int c = 0; c < 4; ++c) {              // broadcast ds_read_b128
            float4 t = QVs[l][c];
            qr[4*c] = t.x; qr[4*c+1] = t.y; qr[4*c+2] = t.z; qr[4*c+3] = t.w;
            float4 u = QVs[l][4 + c];
            vr[4*c] = u.x; vr[4*c+1] = u.y; vr[4*c+2] = u.z; vr[4*c+3] = u.w;
        }
        // two partial sums per column to halve the dependent chain
        float s0a = 0.f, s0b = 0.f, s1a = 0.f, s1b = 0.f;
        #pragma unroll
        for (int k = 0; k < 8; ++k) {
            s0a = fmaf(qr[k],     kv0[k],     s0a);
            s0b = fmaf(qr[k + 8], kv0[k + 8], s0b);
            s1a = fmaf(qr[k],     kv1[k],     s1a);
            s1b = fmaf(qr[k + 8], kv1[k + 8], s1b);
        }
        const float s0 = s0a + s0b;
        const float s1 = s1a + s1b;

        if (s0 > mx0) {
            const float sc = __expf(mx0 - s0);
            sm0 *= sc;
            #pragma unroll
            for (int v = 0; v < DK; ++v) acc0[v] *= sc;
            mx0 = s0;
        }
        if (s1 > mx1) {
            const float sc = __expf(mx1 - s1);
            sm1 *= sc;
            #pragma unroll
            for (int v = 0; v < DK; ++v) acc1[v] *= sc;
            mx1 = s1;
        }
        const float p0 = __expf(s0 - mx0);
        const float p1 = __expf(s1 - mx1);
        sm0 += p0; sm1 += p1;
        #pragma unroll
        for (int v = 0; v < DK; ++v) {
            acc0[v] = fmaf(vr[v], p0, acc0[v]);
            acc1[v] = fmaf(vr[v], p1, acc1[v]);
        }
    }

    // partials: [hb][lc][field][m], coalesced along m
    float* __restrict__ pb = part + ((size_t)(hb * 4 + lc) * 18) * LL;
    pb[m0] = mx0;             pb[m1] = mx1;
    pb[LL + m0] = sm0;        pb[LL + m1] = sm1;
    #pragma unroll
    for (int v = 0; v < DK; ++v) {
        pb[(size_t)(2 + v) * LL + m0] = acc0[v];
        pb[(size_t)(2 + v) * LL + m1] = acc1[v];
    }
}

// ---------------------------------------------------------------------------
// Kernel 3: merge the 4 l-chunk partials, normalize, write head[b][hk][m].
// 384 blocks = (hb, m-half). All reads/writes coalesced along m.
// ---------------------------------------------------------------------------
__global__ __launch_bounds__(256)
void merge_heads(const float* __restrict__ part,
                 float* __restrict__ head)
{
    const int hb = blockIdx.x >> 1;
    const int m = (blockIdx.x & 1) * 256 + threadIdx.x;
    const float* __restrict__ pb = part + (size_t)hb * 4 * 18 * LL + m;

    float mx[4], sm[4];
    #pragma unroll
    for (int c = 0; c < 4; ++c) {
        mx[c] = pb[(size_t)(c * 18) * LL];
        sm[c] = pb[(size_t)(c * 18 + 1) * LL];
    }
    float M = fmaxf(fmaxf(mx[0], mx[1]), fmaxf(mx[2], mx[3]));
    float e[4], S = 0.f;
    #pragma unroll
    for (int c = 0; c < 4; ++c) { e[c] = __expf(mx[c] - M); S = fmaf(sm[c], e[c], S); }
    const float inv = 1.f / S;

    const int h = hb / NB, b = hb % NB;
    float* __restrict__ ho = head + ((size_t)b * DM + h * DK) * LL + m;
    #pragma unroll
    for (int v = 0; v < DK; ++v) {
        float a = 0.f;
        #pragma unroll
        for (int c = 0; c < 4; ++c)
            a = fmaf(pb[(size_t)(c * 18 + 2 + v) * LL], e[c], a);
        ho[(size_t)v * LL] = a * inv;
    }
}

// ---------------------------------------------------------------------------
// Kernel 4: out[b] = Wo[b] @ head[b]. 768 blocks = (b, col-chunk 64, row-q 32).
// 8 accs/thread; head loads coalesced; Wo loads wave-uniform (s_load).
// ---------------------------------------------------------------------------
__global__ __launch_bounds__(256)
void out_proj(const float* __restrict__ Wo,
              const float* __restrict__ head,
              float* __restrict__ out)
{
    const int blk = blockIdx.x;
    const int b   = blk >> 5;
    const int cc  = (blk >> 2) & 7;
    const int rq  = blk & 3;
    const int tid = threadIdx.x;
    const int col = cc * 64 + (tid & 63);
    const int row = rq * 32 + (tid >> 6) * 8;      // wave-uniform row group

    const float* __restrict__ wo = Wo + (size_t)b * DM * DM + (size_t)row * DM;
    const float* __restrict__ hd = head + (size_t)b * DM * LL + col;

    float acc[8];
    #pragma unroll
    for (int i = 0; i < 8; ++i) acc[i] = 0.f;

    #pragma unroll 4
    for (int d = 0; d < DM; ++d) {
        const float hv = hd[(size_t)d * LL];       // coalesced
        #pragma unroll
        for (int i = 0; i < 8; ++i)                // Wo uniform -> s_load
            acc[i] = fmaf(wo[i * DM + d], hv, acc[i]);
    }

    float* __restrict__ ob = out + (size_t)b * DM * LL + (size_t)row * LL + col;
    #pragma unroll
    for (int i = 0; i < 8; ++i)
        ob[(size_t)i * LL] = acc[i];
}

extern "C" void kernel_launch(void* const* d_in, const int* in_sizes, int n_in,
                              void* d_out, int out_size, void* d_ws, size_t ws_size,
                              hipStream_t stream) {
    const float* x  = (const float*)d_in[0];
    const float* Wq = (const float*)d_in[1];
    const float* Wk = (const float*)d_in[2];
    const float* Wv = (const float*)d_in[3];
    const float* Wo = (const float*)d_in[4];
    float* out = (float*)d_out;

    float* ws   = (float*)d_ws;
    float* qv   = ws + QV_OFF;
    float* kbuf = ws + K_OFF;
    float* part = ws + PART_OFF;
    float* head = ws + HEAD_OFF;

    qkv_proj   <<<HB * 4, 256, 0, stream>>>(x, Wq, Wk, Wv, qv, kbuf);
    attn_part  <<<HB * 4, 256, 0, stream>>>(qv, kbuf, part);
    merge_heads<<<HB * 2, 256, 0, stream>>>(part, head);
    out_proj   <<<NB * 32, 256, 0, stream>>>(Wo, head, out);
}